// Round 2
// baseline (28314.215 us; speedup 1.0000x reference)
//
#include <hip/hip_runtime.h>
#include <stdint.h>

#define B_ 128
#define T_ 512
#define D_ 1024
#define H_ 1024

typedef __attribute__((ext_vector_type(8))) short bf16x8;
typedef __attribute__((ext_vector_type(4))) float f32x4;

__device__ __forceinline__ ushort f2bf(float f) {
  union { float f; uint32_t u; } v; v.f = f;
  uint32_t u = v.u + 0x7FFFu + ((v.u >> 16) & 1u);
  return (ushort)(u >> 16);
}
__device__ __forceinline__ float bf2f(ushort s) {
  union { uint32_t u; float f; } v; v.u = ((uint32_t)s) << 16;
  return v.f;
}

__device__ __forceinline__ void store_xp(float* p, float v) { *p = v; }
__device__ __forceinline__ void store_xp(ushort* p, float v) { *p = f2bf(v); }
__device__ __forceinline__ float load_xp(const float* p) { return *p; }
__device__ __forceinline__ float load_xp(const ushort* p) { return bf2f(*p); }

// ---------------- W_hh -> (hi, lo) bf16 split ----------------
__global__ void wsplit_kernel(const float* __restrict__ W,
                              ushort* __restrict__ hi, ushort* __restrict__ lo,
                              int n) {
  int i = blockIdx.x * blockDim.x + threadIdx.x;
  if (i < n) {
    float w = W[i];
    ushort h = f2bf(w);
    hi[i] = h;
    lo[i] = f2bf(w - bf2f(h));
  }
}

// ---------------- zero workspace region ----------------
__global__ void hzero_kernel(uint4* __restrict__ p, int n4) {
  int i = blockIdx.x * blockDim.x + threadIdx.x;
  if (i < n4) p[i] = make_uint4(0, 0, 0, 0);
}

// ---------------- xp = x @ W_ih^T + b_ih + b_hh, stored [T,B,H] ----------------
template <typename XPT>
__global__ __launch_bounds__(256) void xp_gemm(
    const float* __restrict__ x, const float* __restrict__ Wih,
    const float* __restrict__ bih, const float* __restrict__ bhh,
    XPT* __restrict__ xp) {
  __shared__ __align__(16) ushort As[128][40];
  __shared__ __align__(16) ushort Bs[128][40];
  const int tid = threadIdx.x;
  const int lane = tid & 63;
  const int w = tid >> 6;
  const int wm = w >> 1, wn = w & 1;
  const int bm = blockIdx.x;  // 512 M-tiles
  const int bn = blockIdx.y;  // 8 N-tiles

  f32x4 acc[4][4] = {};

  for (int kt = 0; kt < D_ / 32; ++kt) {
    __syncthreads();
#pragma unroll
    for (int i = 0; i < 4; ++i) {
      int c = tid + i * 256;      // 0..1023
      int isB = c >> 9;           // 0: A chunk, 1: B chunk
      int cc = c & 511;
      int row = cc >> 2;          // 0..127
      int col8 = (cc & 3) << 3;   // 0,8,16,24
      const float* src = isB
          ? (Wih + (size_t)(bn * 128 + row) * D_ + kt * 32 + col8)
          : (x + (size_t)(bm * 128 + row) * D_ + kt * 32 + col8);
      float4 f0 = *(const float4*)(src);
      float4 f1 = *(const float4*)(src + 4);
      uint32_t p0 = (uint32_t)f2bf(f0.x) | ((uint32_t)f2bf(f0.y) << 16);
      uint32_t p1 = (uint32_t)f2bf(f0.z) | ((uint32_t)f2bf(f0.w) << 16);
      uint32_t p2 = (uint32_t)f2bf(f1.x) | ((uint32_t)f2bf(f1.y) << 16);
      uint32_t p3 = (uint32_t)f2bf(f1.z) | ((uint32_t)f2bf(f1.w) << 16);
      uint4 pk = make_uint4(p0, p1, p2, p3);
      ushort* dst = isB ? &Bs[row][col8] : &As[row][col8];
      *(uint4*)dst = pk;
    }
    __syncthreads();

    bf16x8 af[4], bfr[4];
#pragma unroll
    for (int fm = 0; fm < 4; ++fm)
      af[fm] = *(const bf16x8*)&As[wm * 64 + fm * 16 + (lane & 15)][(lane >> 4) * 8];
#pragma unroll
    for (int fn = 0; fn < 4; ++fn)
      bfr[fn] = *(const bf16x8*)&Bs[wn * 64 + fn * 16 + (lane & 15)][(lane >> 4) * 8];
#pragma unroll
    for (int fm = 0; fm < 4; ++fm)
#pragma unroll
      for (int fn = 0; fn < 4; ++fn)
        acc[fm][fn] = __builtin_amdgcn_mfma_f32_16x16x32_bf16(
            af[fm], bfr[fn], acc[fm][fn], 0, 0, 0);
  }

  float bias[4];
#pragma unroll
  for (int fn = 0; fn < 4; ++fn) {
    int j = bn * 128 + wn * 64 + fn * 16 + (lane & 15);
    bias[fn] = bih[j] + bhh[j];
  }
#pragma unroll
  for (int fm = 0; fm < 4; ++fm) {
#pragma unroll
    for (int r = 0; r < 4; ++r) {
      int m = bm * 128 + wm * 64 + fm * 16 + ((lane >> 4) * 4) + r;
      int t = m & (T_ - 1);
      int b = m >> 9;  // m / T_
      size_t base = (size_t)t * (B_ * H_) + (size_t)b * H_;
#pragma unroll
      for (int fn = 0; fn < 4; ++fn) {
        int j = bn * 128 + wn * 64 + fn * 16 + (lane & 15);
        store_xp(xp + base + j, acc[fm][fn][r] + bias[fn]);
      }
    }
  }
}

// ---------------- persistent recurrence kernel ----------------
// Grid: (64 col-WGs, 4 batch-groups). Each WG: 16 output cols x 32 batches.
// W tile (16 rows x 1024, hi+lo) resident in LDS for all 512 steps.
// 4 waves: (batch-tile bt in {0,1}) x (K-half kh in {0,1}); 2-way K reduce in LDS.
// Per-step sync: group-local 64-WG barrier (monotonic atomic counter).
template <typename XPT>
__global__ __launch_bounds__(256) void rnn_persist(
    const ushort* __restrict__ Whi, const ushort* __restrict__ Wlo,
    const XPT* __restrict__ xp,
    ushort* __restrict__ hhi_a, ushort* __restrict__ hhi_b,
    ushort* __restrict__ hlo_a, ushort* __restrict__ hlo_b,
    unsigned* __restrict__ cnt,
    float* __restrict__ out) {
  __shared__ __align__(16) ushort Whs[16][1032];
  __shared__ __align__(16) ushort Wls[16][1032];
  __shared__ __align__(16) float red[2][64][4];

  const int c = blockIdx.x;   // col group: cols [c*16, c*16+16)
  const int bg = blockIdx.y;  // batch group: batches [bg*32, bg*32+32)
  const int tid = threadIdx.x;
  const int lane = tid & 63;
  const int w = tid >> 6;
  const int bt = w & 1;   // batch tile (16 batches)
  const int kh = w >> 1;  // K half (512)

  // ---- load W tile into LDS once ----
  for (int i = tid; i < 2048; i += 256) {   // 16 rows x 128 uint4/row
    int row = i >> 7;
    int kc = (i & 127) << 3;  // element offset
    *(uint4*)&Whs[row][kc] = *(const uint4*)(Whi + (size_t)(c * 16 + row) * H_ + kc);
    *(uint4*)&Wls[row][kc] = *(const uint4*)(Wlo + (size_t)(c * 16 + row) * H_ + kc);
  }
  __syncthreads();

  const int jl = lane & 15;
  const int jglob = c * 16 + jl;
  const int arow = bg * 32 + bt * 16 + (lane & 15);
  const int koff = kh * 512 + ((lane >> 4) << 3);
  const size_t hbase = (size_t)arow * H_ + koff;
  unsigned* mycnt = cnt + bg * 32;  // 128B-spaced counters

  for (int t = 0; t < T_; ++t) {
    const ushort* Hh = (t & 1) ? hhi_b : hhi_a;
    const ushort* Hl = (t & 1) ? hlo_b : hlo_a;
    ushort* Hhn = (t & 1) ? hhi_a : hhi_b;
    ushort* Hln = (t & 1) ? hlo_a : hlo_b;

    // A fragments: h hi/lo for this wave's (batch-tile, K-half)
    bf16x8 ah[16], al[16];
#pragma unroll
    for (int ks = 0; ks < 16; ++ks) {
      ah[ks] = *(const bf16x8*)(Hh + hbase + ks * 32);
      al[ks] = *(const bf16x8*)(Hl + hbase + ks * 32);
    }

    // xp prefetch (epilogue waves only)
    float xpv[4];
    if (kh == 0) {
#pragma unroll
      for (int r = 0; r < 4; ++r) {
        int row = bg * 32 + bt * 16 + ((lane >> 4) << 2) + r;
        xpv[r] = load_xp(xp + (size_t)t * (B_ * H_) + (size_t)row * H_ + jglob);
      }
    }

    f32x4 acc = {};
#pragma unroll
    for (int ks = 0; ks < 16; ++ks) {
      int kidx = kh * 512 + ks * 32 + ((lane >> 4) << 3);
      bf16x8 bh = *(const bf16x8*)&Whs[jl][kidx];
      bf16x8 bl = *(const bf16x8*)&Wls[jl][kidx];
      acc = __builtin_amdgcn_mfma_f32_16x16x32_bf16(ah[ks], bh, acc, 0, 0, 0);
      acc = __builtin_amdgcn_mfma_f32_16x16x32_bf16(al[ks], bh, acc, 0, 0, 0);
      acc = __builtin_amdgcn_mfma_f32_16x16x32_bf16(ah[ks], bl, acc, 0, 0, 0);
    }

    // 2-way K reduce via LDS
    if (kh == 1) *(f32x4*)&red[bt][lane][0] = acc;
    __syncthreads();
    if (kh == 0) {
      f32x4 o = *(const f32x4*)&red[bt][lane][0];
      acc = acc + o;
#pragma unroll
      for (int r = 0; r < 4; ++r) {
        int row = bg * 32 + bt * 16 + ((lane >> 4) << 2) + r;
        float pre = acc[r] + xpv[r];
        float hn = tanhf(pre);
        ushort hb = f2bf(hn);
        Hhn[(size_t)row * H_ + jglob] = hb;
        Hln[(size_t)row * H_ + jglob] = f2bf(hn - bf2f(hb));
        if (t == T_ - 1) out[(size_t)row * H_ + jglob] = hn;
      }
    }

    // group-local barrier: release writes, arrive, spin, acquire
    __threadfence();
    __syncthreads();
    if (tid == 0) {
      atomicAdd(mycnt, 1u);
      unsigned target = (unsigned)(t + 1) * 64u;
      while (__hip_atomic_load(mycnt, __ATOMIC_RELAXED, __HIP_MEMORY_SCOPE_AGENT) < target)
        __builtin_amdgcn_s_sleep(1);
    }
    __syncthreads();
    __threadfence();
  }
}

// ---------------- launch ----------------
extern "C" void kernel_launch(void* const* d_in, const int* in_sizes, int n_in,
                              void* d_out, int out_size, void* d_ws, size_t ws_size,
                              hipStream_t stream) {
  const float* x    = (const float*)d_in[0];
  const float* W_ih = (const float*)d_in[1];
  const float* W_hh = (const float*)d_in[2];
  const float* b_ih = (const float*)d_in[3];
  const float* b_hh = (const float*)d_in[4];
  float* out = (float*)d_out;

  const size_t xp_f32_bytes = (size_t)T_ * B_ * H_ * 4;   // 256 MB
  const size_t xp_bf_bytes  = xp_f32_bytes / 2;           // 128 MB
  const size_t wsp_bytes    = 2 * (size_t)H_ * H_ * 2;    // 4 MB (hi+lo)
  const size_t h_bytes      = 4 * (size_t)B_ * H_ * 2;    // 1 MB (hi/lo x 2 bufs)
  const size_t cnt_bytes    = 4096;

  bool fp32xp = ws_size >= xp_f32_bytes + wsp_bytes + h_bytes + cnt_bytes;
  bool bf16xp = !fp32xp && ws_size >= xp_bf_bytes + wsp_bytes + h_bytes + cnt_bytes;
  if (!fp32xp && !bf16xp) return;

  char* p = (char*)d_ws;
  size_t xp_bytes = fp32xp ? xp_f32_bytes : xp_bf_bytes;
  char* xp_raw = p;                       p += xp_bytes;
  ushort* Whi = (ushort*)p;               p += (size_t)H_ * H_ * 2;
  ushort* Wlo = (ushort*)p;               p += (size_t)H_ * H_ * 2;
  ushort* hbuf = (ushort*)p;              p += h_bytes;
  unsigned* cnt = (unsigned*)p;
  ushort* hhi_a = hbuf;
  ushort* hhi_b = hbuf + (size_t)B_ * H_;
  ushort* hlo_a = hbuf + 2 * (size_t)B_ * H_;
  ushort* hlo_b = hbuf + 3 * (size_t)B_ * H_;

  // 1) split W_hh
  {
    int n = H_ * H_;
    wsplit_kernel<<<(n + 255) / 256, 256, 0, stream>>>(W_hh, Whi, Wlo, n);
  }
  // 2) zero h buffers + barrier counters
  {
    int n4 = (int)((h_bytes + cnt_bytes) / 16);
    hzero_kernel<<<(n4 + 255) / 256, 256, 0, stream>>>((uint4*)hbuf, n4);
  }
  // 3) xp GEMM
  dim3 gxp(512, 8);
  if (fp32xp)
    xp_gemm<float><<<gxp, 256, 0, stream>>>(x, W_ih, b_ih, b_hh, (float*)xp_raw);
  else
    xp_gemm<ushort><<<gxp, 256, 0, stream>>>(x, W_ih, b_ih, b_hh, (ushort*)xp_raw);

  // 4) persistent recurrence: 64 col-WGs x 4 batch-groups
  dim3 gp(64, 4);
  if (fp32xp)
    rnn_persist<float><<<gp, 256, 0, stream>>>(Whi, Wlo, (const float*)xp_raw,
                                               hhi_a, hhi_b, hlo_a, hlo_b, cnt, out);
  else
    rnn_persist<ushort><<<gp, 256, 0, stream>>>(Whi, Wlo, (const ushort*)xp_raw,
                                                hhi_a, hhi_b, hlo_a, hlo_b, cnt, out);
}

// Round 3
// 3609.987 us; speedup vs baseline: 7.8433x; 7.8433x over previous
//
#include <hip/hip_runtime.h>
#include <stdint.h>

#define B_ 128
#define T_ 512
#define D_ 1024
#define H_ 1024

typedef __attribute__((ext_vector_type(8))) short bf16x8;
typedef __attribute__((ext_vector_type(4))) float f32x4;
typedef unsigned int u32;
typedef unsigned long long u64;

__device__ __forceinline__ ushort f2bf(float f) {
  union { float f; uint32_t u; } v; v.f = f;
  uint32_t u = v.u + 0x7FFFu + ((v.u >> 16) & 1u);
  return (ushort)(u >> 16);
}
__device__ __forceinline__ float bf2f(ushort s) {
  union { uint32_t u; float f; } v; v.u = ((uint32_t)s) << 16;
  return v.f;
}

__device__ __forceinline__ void store_xp(float* p, float v) { *p = v; }
__device__ __forceinline__ void store_xp(ushort* p, float v) { *p = f2bf(v); }
__device__ __forceinline__ float load_xp(const float* p) { return *p; }
__device__ __forceinline__ float load_xp(const ushort* p) { return bf2f(*p); }

// ---------------- W_hh -> (hi, lo) bf16 split ----------------
__global__ void wsplit_kernel(const float* __restrict__ W,
                              ushort* __restrict__ hi, ushort* __restrict__ lo,
                              int n) {
  int i = blockIdx.x * blockDim.x + threadIdx.x;
  if (i < n) {
    float w = W[i];
    ushort h = f2bf(w);
    hi[i] = h;
    lo[i] = f2bf(w - bf2f(h));
  }
}

// ---------------- zero workspace region ----------------
__global__ void hzero_kernel(uint4* __restrict__ p, int n4) {
  int i = blockIdx.x * blockDim.x + threadIdx.x;
  if (i < n4) p[i] = make_uint4(0, 0, 0, 0);
}

// ---------------- xp = x @ W_ih^T + b_ih + b_hh, stored [T,B,H] ----------------
template <typename XPT>
__global__ __launch_bounds__(256) void xp_gemm(
    const float* __restrict__ x, const float* __restrict__ Wih,
    const float* __restrict__ bih, const float* __restrict__ bhh,
    XPT* __restrict__ xp) {
  __shared__ __align__(16) ushort As[128][40];
  __shared__ __align__(16) ushort Bs[128][40];
  const int tid = threadIdx.x;
  const int lane = tid & 63;
  const int w = tid >> 6;
  const int wm = w >> 1, wn = w & 1;
  const int bm = blockIdx.x;  // 512 M-tiles
  const int bn = blockIdx.y;  // 8 N-tiles

  f32x4 acc[4][4] = {};

  for (int kt = 0; kt < D_ / 32; ++kt) {
    __syncthreads();
#pragma unroll
    for (int i = 0; i < 4; ++i) {
      int c = tid + i * 256;      // 0..1023
      int isB = c >> 9;           // 0: A chunk, 1: B chunk
      int cc = c & 511;
      int row = cc >> 2;          // 0..127
      int col8 = (cc & 3) << 3;   // 0,8,16,24
      const float* src = isB
          ? (Wih + (size_t)(bn * 128 + row) * D_ + kt * 32 + col8)
          : (x + (size_t)(bm * 128 + row) * D_ + kt * 32 + col8);
      float4 f0 = *(const float4*)(src);
      float4 f1 = *(const float4*)(src + 4);
      uint32_t p0 = (uint32_t)f2bf(f0.x) | ((uint32_t)f2bf(f0.y) << 16);
      uint32_t p1 = (uint32_t)f2bf(f0.z) | ((uint32_t)f2bf(f0.w) << 16);
      uint32_t p2 = (uint32_t)f2bf(f1.x) | ((uint32_t)f2bf(f1.y) << 16);
      uint32_t p3 = (uint32_t)f2bf(f1.z) | ((uint32_t)f2bf(f1.w) << 16);
      uint4 pk = make_uint4(p0, p1, p2, p3);
      ushort* dst = isB ? &Bs[row][col8] : &As[row][col8];
      *(uint4*)dst = pk;
    }
    __syncthreads();

    bf16x8 af[4], bfr[4];
#pragma unroll
    for (int fm = 0; fm < 4; ++fm)
      af[fm] = *(const bf16x8*)&As[wm * 64 + fm * 16 + (lane & 15)][(lane >> 4) * 8];
#pragma unroll
    for (int fn = 0; fn < 4; ++fn)
      bfr[fn] = *(const bf16x8*)&Bs[wn * 64 + fn * 16 + (lane & 15)][(lane >> 4) * 8];
#pragma unroll
    for (int fm = 0; fm < 4; ++fm)
#pragma unroll
      for (int fn = 0; fn < 4; ++fn)
        acc[fm][fn] = __builtin_amdgcn_mfma_f32_16x16x32_bf16(
            af[fm], bfr[fn], acc[fm][fn], 0, 0, 0);
  }

  float bias[4];
#pragma unroll
  for (int fn = 0; fn < 4; ++fn) {
    int j = bn * 128 + wn * 64 + fn * 16 + (lane & 15);
    bias[fn] = bih[j] + bhh[j];
  }
#pragma unroll
  for (int fm = 0; fm < 4; ++fm) {
#pragma unroll
    for (int r = 0; r < 4; ++r) {
      int m = bm * 128 + wm * 64 + fm * 16 + ((lane >> 4) * 4) + r;
      int t = m & (T_ - 1);
      int b = m >> 9;  // m / T_
      size_t base = (size_t)t * (B_ * H_) + (size_t)b * H_;
#pragma unroll
      for (int fn = 0; fn < 4; ++fn) {
        int j = bn * 128 + wn * 64 + fn * 16 + (lane & 15);
        store_xp(xp + base + j, acc[fm][fn][r] + bias[fn]);
      }
    }
  }
}

// ---------------- persistent recurrence v2: fence-free ----------------
// 256 WGs: replica = bid&7 (16 batches), col-group wgc = bid>>3 (32 cols).
// Wave = K-quarter (K=256). W_hh frags in REGISTERS (loaded once).
// h exchanged as packed u32 (bf16 hi | lo<<16) via relaxed AGENT atomics
// (LLC-coherent, no L2 fences). Single-writer per-WG flag lines; readers
// poll 32 flags lane-parallel. One __syncthreads per step (K-reduce);
// red-buffer reuse across steps is gated by the own-WG flag.
template <typename XPT>
__global__ __launch_bounds__(256, 1) void rnn_persist(
    const ushort* __restrict__ Whi, const ushort* __restrict__ Wlo,
    const XPT* __restrict__ xp,
    u32* __restrict__ hpk,   // [2][B_][H_] packed hi|lo
    u32* __restrict__ flg,   // [256][16] (64B-spaced single-writer flags)
    float* __restrict__ out) {
  __shared__ __align__(16) float red[3][2][64][4];  // 6 KB

  const int bid = blockIdx.x;
  const int rep = bid & 7;    // replica: batches [rep*16, rep*16+16)
  const int wgc = bid >> 3;   // cols [wgc*32, wgc*32+32)
  const int tid = threadIdx.x;
  const int lane = tid & 63;
  const int kq = tid >> 6;    // wave = K-quarter
  const int r16 = lane & 15;
  const int kg = lane >> 4;   // 0..3

  // ---- preload W fragments into registers (static, 128 VGPR) ----
  bf16x8 wbh[8][2], wbl[8][2];
#pragma unroll
  for (int ks = 0; ks < 8; ++ks) {
#pragma unroll
    for (int nf = 0; nf < 2; ++nf) {
      int col = wgc * 32 + nf * 16 + r16;
      int k = kq * 256 + ks * 32 + kg * 8;
      wbh[ks][nf] = *(const bf16x8*)(Whi + (size_t)col * H_ + k);
      wbl[ks][nf] = *(const bf16x8*)(Wlo + (size_t)col * H_ + k);
    }
  }

  const int arow = rep * 16 + r16;                      // A (h) row
  const size_t abase = ((size_t)arow * H_ + kq * 256 + kg * 8) >> 1;  // u64 idx
  u32* myflag = flg + (size_t)(rep * 32 + wgc) * 16;
  u32* repflags = flg + (size_t)rep * 32 * 16;

  for (int t = 0; t < T_; ++t) {
    // ---- wait: all 32 WGs of this replica finished step t-1 ----
    if (t) {
      for (;;) {
        u32 v = 0xFFFFFFFFu;
        if (lane < 32)
          v = __hip_atomic_load(repflags + (size_t)lane * 16,
                                __ATOMIC_RELAXED, __HIP_MEMORY_SCOPE_AGENT);
        if (__all((int)(v >= (u32)t))) break;
        __builtin_amdgcn_s_sleep(1);
      }
    }

    const u64* Hq = (const u64*)(hpk + (size_t)(t & 1) * (B_ * H_));
    u32* Hn = hpk + (size_t)((t + 1) & 1) * (B_ * H_);

    // ---- batch-issue all h loads for this wave's K-quarter (32 x 8B) ----
    u64 aq[8][4];
#pragma unroll
    for (int ks = 0; ks < 8; ++ks)
#pragma unroll
      for (int j = 0; j < 4; ++j)
        aq[ks][j] = __hip_atomic_load(Hq + abase + ks * 16 + j,
                                      __ATOMIC_RELAXED, __HIP_MEMORY_SCOPE_AGENT);

    // xp prefetch (epilogue wave only); xp is static -> normal cached loads
    float xpv[2][4];
    if (kq == 0) {
#pragma unroll
      for (int nf = 0; nf < 2; ++nf)
#pragma unroll
        for (int r = 0; r < 4; ++r) {
          int row = rep * 16 + kg * 4 + r;
          int col = wgc * 32 + nf * 16 + r16;
          xpv[nf][r] = load_xp(xp + (size_t)t * (B_ * H_) + (size_t)row * H_ + col);
        }
    }

    f32x4 acc[2] = {};
#pragma unroll
    for (int ks = 0; ks < 8; ++ks) {
      union { u32 u[4]; bf16x8 v; } ah, al;
#pragma unroll
      for (int j = 0; j < 4; ++j) {
        u32 e0 = (u32)aq[ks][j];
        u32 e1 = (u32)(aq[ks][j] >> 32);
        ah.u[j] = __builtin_amdgcn_perm(e1, e0, 0x05040100u);  // lo16s
        al.u[j] = __builtin_amdgcn_perm(e1, e0, 0x07060302u);  // hi16s
      }
#pragma unroll
      for (int nf = 0; nf < 2; ++nf) {
        acc[nf] = __builtin_amdgcn_mfma_f32_16x16x32_bf16(ah.v, wbh[ks][nf], acc[nf], 0, 0, 0);
        acc[nf] = __builtin_amdgcn_mfma_f32_16x16x32_bf16(al.v, wbh[ks][nf], acc[nf], 0, 0, 0);
        acc[nf] = __builtin_amdgcn_mfma_f32_16x16x32_bf16(ah.v, wbl[ks][nf], acc[nf], 0, 0, 0);
      }
    }

    // ---- 4-way K reduce + epilogue on wave 0 ----
    if (kq > 0) {
      *(f32x4*)&red[kq - 1][0][lane][0] = acc[0];
      *(f32x4*)&red[kq - 1][1][lane][0] = acc[1];
    }
    __syncthreads();
    if (kq == 0) {
#pragma unroll
      for (int q = 0; q < 3; ++q) {
        acc[0] += *(const f32x4*)&red[q][0][lane][0];
        acc[1] += *(const f32x4*)&red[q][1][lane][0];
      }
#pragma unroll
      for (int nf = 0; nf < 2; ++nf)
#pragma unroll
        for (int r = 0; r < 4; ++r) {
          int row = rep * 16 + kg * 4 + r;
          int col = wgc * 32 + nf * 16 + r16;
          float pre = acc[nf][r] + xpv[nf][r];
          float hn = tanhf(pre);
          ushort hb = f2bf(hn);
          ushort lb = f2bf(hn - bf2f(hb));
          u32 pk = (u32)hb | ((u32)lb << 16);
          __hip_atomic_store(Hn + (size_t)row * H_ + col, pk,
                             __ATOMIC_RELAXED, __HIP_MEMORY_SCOPE_AGENT);
          if (t == T_ - 1) out[(size_t)row * H_ + col] = hn;
        }
      // order: h stores complete (at LLC) before flag store issues
      asm volatile("s_waitcnt vmcnt(0)" ::: "memory");
      if (lane == 0)
        __hip_atomic_store(myflag, (u32)(t + 1),
                           __ATOMIC_RELAXED, __HIP_MEMORY_SCOPE_AGENT);
    }
  }
}

// ---------------- launch ----------------
extern "C" void kernel_launch(void* const* d_in, const int* in_sizes, int n_in,
                              void* d_out, int out_size, void* d_ws, size_t ws_size,
                              hipStream_t stream) {
  const float* x    = (const float*)d_in[0];
  const float* W_ih = (const float*)d_in[1];
  const float* W_hh = (const float*)d_in[2];
  const float* b_ih = (const float*)d_in[3];
  const float* b_hh = (const float*)d_in[4];
  float* out = (float*)d_out;

  const size_t xp_f32_bytes = (size_t)T_ * B_ * H_ * 4;   // 256 MB
  const size_t xp_bf_bytes  = xp_f32_bytes / 2;           // 128 MB
  const size_t wsp_bytes    = 2 * (size_t)H_ * H_ * 2;    // 4 MB (hi+lo)
  const size_t hpk_bytes    = 2 * (size_t)B_ * H_ * 4;    // 1 MB packed, dbuf
  const size_t flg_bytes    = 256 * 64;                   // 16 KB

  bool fp32xp = ws_size >= xp_f32_bytes + wsp_bytes + hpk_bytes + flg_bytes;
  bool bf16xp = !fp32xp && ws_size >= xp_bf_bytes + wsp_bytes + hpk_bytes + flg_bytes;
  if (!fp32xp && !bf16xp) return;

  char* p = (char*)d_ws;
  size_t xp_bytes = fp32xp ? xp_f32_bytes : xp_bf_bytes;
  char* xp_raw = p;                       p += xp_bytes;
  ushort* Whi = (ushort*)p;               p += (size_t)H_ * H_ * 2;
  ushort* Wlo = (ushort*)p;               p += (size_t)H_ * H_ * 2;
  u32* hpk = (u32*)p;                     p += hpk_bytes;
  u32* flg = (u32*)p;

  // 1) split W_hh
  {
    int n = H_ * H_;
    wsplit_kernel<<<(n + 255) / 256, 256, 0, stream>>>(W_hh, Whi, Wlo, n);
  }
  // 2) zero h buffers + flags (contiguous)
  {
    int n4 = (int)((hpk_bytes + flg_bytes) / 16);
    hzero_kernel<<<(n4 + 255) / 256, 256, 0, stream>>>((uint4*)hpk, n4);
  }
  // 3) xp GEMM
  dim3 gxp(512, 8);
  if (fp32xp)
    xp_gemm<float><<<gxp, 256, 0, stream>>>(x, W_ih, b_ih, b_hh, (float*)xp_raw);
  else
    xp_gemm<ushort><<<gxp, 256, 0, stream>>>(x, W_ih, b_ih, b_hh, (ushort*)xp_raw);

  // 4) persistent recurrence (256 WGs, co-resident; round 2 proved residency)
  if (fp32xp)
    rnn_persist<float><<<256, 256, 0, stream>>>(Whi, Wlo, (const float*)xp_raw,
                                                hpk, flg, out);
  else
    rnn_persist<ushort><<<256, 256, 0, stream>>>(Whi, Wlo, (const ushort*)xp_raw,
                                                 hpk, flg, out);
}